// Round 2
// baseline (702.945 us; speedup 1.0000x reference)
//
#include <hip/hip_runtime.h>
#include <math.h>

// Problem constants (fixed by reference setup_inputs)
constexpr int B = 4, H = 8, N = 2048, C = 512;
constexpr float TAU = 1.5f;
constexpr int MIN_TOKENS = 32;
constexpr float EPS = 1e-6f;

// ---------------------------------------------------------------------------
// Kernel 1: per-(b,i) row entropy of head-mean attention.
// One block per (b,i), 256 threads. All 16 float4 loads per thread are issued
// into a static-indexed register array before any compute -> 16 loads in
// flight per thread for latency hiding. Reads 512 MiB exactly once.
// ---------------------------------------------------------------------------
__global__ __launch_bounds__(256) void entropy_kernel(
    const float* __restrict__ attn, float* __restrict__ ent_out) {
    const int bi = blockIdx.x;          // b*N + i
    const int b  = bi >> 11;            // / N
    const int i  = bi & (N - 1);
    const int t  = threadIdx.x;

    const float* base = attn + ((size_t)(b * H) * N + i) * (size_t)N;
    const size_t hstride = (size_t)N * N;

    // issue all 16 loads (2 j-chunks x 8 heads), fully static-indexed
    float4 v[2][8];
#pragma unroll
    for (int it = 0; it < 2; ++it) {
        const int j = it * 1024 + t * 4;
#pragma unroll
        for (int h = 0; h < H; ++h) {
            v[it][h] = *reinterpret_cast<const float4*>(base + h * hstride + j);
        }
    }

    float ent = 0.f;
#pragma unroll
    for (int it = 0; it < 2; ++it) {
        float4 s = v[it][0];
#pragma unroll
        for (int h = 1; h < H; ++h) {
            s.x += v[it][h].x; s.y += v[it][h].y;
            s.z += v[it][h].z; s.w += v[it][h].w;
        }
        float p;
        p = s.x * 0.125f; ent += p * logf(p + EPS);
        p = s.y * 0.125f; ent += p * logf(p + EPS);
        p = s.z * 0.125f; ent += p * logf(p + EPS);
        p = s.w * 0.125f; ent += p * logf(p + EPS);
    }

    // block reduce (4 waves of 64)
#pragma unroll
    for (int off = 32; off > 0; off >>= 1) ent += __shfl_down(ent, off, 64);
    __shared__ float ws[4];
    const int wid = t >> 6, lane = t & 63;
    if (lane == 0) ws[wid] = ent;
    __syncthreads();
    if (t == 0) ent_out[bi] = -(ws[0] + ws[1] + ws[2] + ws[3]);
}

// ---------------------------------------------------------------------------
// Kernel 2: selection — ONE WAVE PER BATCH, zero barriers, zero LDS.
// Single block of 256 threads = 4 waves; wave w handles batch w.
// Each lane owns 32 consecutive entropies [lane*32, lane*32+32) in registers.
//  - count via lane-local sum + 6-step shfl_up inclusive scan
//  - count >= MIN_TOKENS: stable compaction (lane order == index order)
//  - else: 32 x wave argmax via shfl_xor (value desc, tie -> lower index,
//    matching jax.lax.top_k); invalidation via static unrolled predication
//    (no runtime register indexing -> no scratch spill)
// ---------------------------------------------------------------------------
__global__ __launch_bounds__(256) void select_kernel(
    const float* __restrict__ ent, int* __restrict__ idx_out,
    int* __restrict__ keep_out) {
    const int t = threadIdx.x;
    const int b = t >> 6;           // wave id == batch id
    const int lane = t & 63;

    float v[32];
#pragma unroll
    for (int u = 0; u < 8; ++u) {
        const float4 x = *reinterpret_cast<const float4*>(
            ent + b * N + lane * 32 + u * 4);
        v[u * 4 + 0] = x.x; v[u * 4 + 1] = x.y;
        v[u * 4 + 2] = x.z; v[u * 4 + 3] = x.w;
    }

    int cnt = 0;
#pragma unroll
    for (int j = 0; j < 32; ++j) cnt += (v[j] > TAU) ? 1 : 0;

    // wave inclusive scan of per-lane counts
    int incl = cnt;
#pragma unroll
    for (int off = 1; off < 64; off <<= 1) {
        const int o = __shfl_up(incl, off, 64);
        if (lane >= off) incl += o;
    }
    const int total = __shfl(incl, 63, 64);
    const int excl = incl - cnt;

    if (total >= MIN_TOKENS) {
        int pos = excl;
#pragma unroll
        for (int j = 0; j < 32; ++j) {
            if (v[j] > TAU) idx_out[b * N + pos++] = lane * 32 + j;
        }
        if (lane == 0) keep_out[b] = total;
    } else {
        for (int k = 0; k < MIN_TOKENS; ++k) {
            // lane-local argmax (ascending j, strict > keeps lowest index on tie)
            float bv = -INFINITY; int bj = N;
#pragma unroll
            for (int j = 0; j < 32; ++j) {
                if (v[j] > bv) { bv = v[j]; bj = lane * 32 + j; }
            }
            // wave argmax, tie -> smaller index; all lanes converge to winner
#pragma unroll
            for (int off = 32; off > 0; off >>= 1) {
                const float ov = __shfl_xor(bv, off, 64);
                const int   oj = __shfl_xor(bj, off, 64);
                if (ov > bv || (ov == bv && oj < bj)) { bv = ov; bj = oj; }
            }
            if (lane == 0) idx_out[b * N + k] = bj;
            // invalidate winner (static indices only -> stays in registers)
#pragma unroll
            for (int j = 0; j < 32; ++j) {
                if (lane * 32 + j == bj) v[j] = -INFINITY;
            }
        }
        if (lane == 0) keep_out[b] = MIN_TOKENS;
    }
}

// ---------------------------------------------------------------------------
// Kernel 3: gather + zero-pad. One block per output row (b,r); 128 threads
// move 128 float4 = 512 floats. Rows >= keep_len[b] are zeroed (d_out is
// poisoned 0xAA before every launch).
// ---------------------------------------------------------------------------
__global__ __launch_bounds__(128) void gather_kernel(
    const float* __restrict__ tokens, const int* __restrict__ idx,
    const int* __restrict__ keep, float* __restrict__ out) {
    const int br = blockIdx.x;          // b*N + r
    const int b  = br >> 11;
    const int r  = br & (N - 1);
    const int t  = threadIdx.x;

    float4* orow = reinterpret_cast<float4*>(out + (size_t)br * C);
    if (r < keep[b]) {
        const int src = idx[br];
        const float4* srow = reinterpret_cast<const float4*>(
            tokens + ((size_t)b * N + src) * (size_t)C);
        orow[t] = srow[t];
    } else {
        orow[t] = make_float4(0.f, 0.f, 0.f, 0.f);
    }
}

extern "C" void kernel_launch(void* const* d_in, const int* in_sizes, int n_in,
                              void* d_out, int out_size, void* d_ws, size_t ws_size,
                              hipStream_t stream) {
    const float* tokens = (const float*)d_in[0];  // (B, N, C) f32
    const float* attn   = (const float*)d_in[1];  // (B, H, N, N) f32
    float* out = (float*)d_out;                   // (B, N, C) f32

    // workspace layout: entropy (B*N f32) | idx (B*N i32) | keep (B i32)
    float* ent_ws  = (float*)d_ws;
    int*   idx_ws  = (int*)((char*)d_ws + (size_t)B * N * sizeof(float));
    int*   keep_ws = (int*)((char*)d_ws + 2 * (size_t)B * N * sizeof(float));

    entropy_kernel<<<B * N, 256, 0, stream>>>(attn, ent_ws);
    select_kernel<<<1, 256, 0, stream>>>(ent_ws, idx_ws, keep_ws);
    gather_kernel<<<B * N, 128, 0, stream>>>(tokens, idx_ws, keep_ws, out);
}